// Round 7
// baseline (217.120 us; speedup 1.0000x reference)
//
#include <hip/hip_runtime.h>

typedef unsigned short u16;
typedef unsigned int   u32;
typedef float f32x4  __attribute__((ext_vector_type(4)));
typedef __bf16 bf16x8 __attribute__((ext_vector_type(8)));

__device__ __forceinline__ u16 f2bf(float f){
  u32 u = __float_as_uint(f);
  u += 0x7fffu + ((u >> 16) & 1u);          // RNE
  return (u16)(u >> 16);
}

// async global->LDS, 16B per lane; LDS dest is wave-uniform base + lane*16
__device__ __forceinline__ void gld16(const void* g, void* l){
  __builtin_amdgcn_global_load_lds((const __attribute__((address_space(1))) u32*)g,
                                   (__attribute__((address_space(3))) u32*)l, 16, 0, 0);
}

// ---------------- weight conversion: fp32->bf16, sigs->ternary bf16 ----------------
__global__ __launch_bounds__(256) void convert_kernel(
    const float* __restrict__ qw, const float* __restrict__ ow,
    const float* __restrict__ sg,
    u16* __restrict__ qwb, u16* __restrict__ owb, u16* __restrict__ sgb){
  int i = (blockIdx.x * 256 + threadIdx.x) * 4;   // 1,048,576 elements each
  f32x4 a = *(const f32x4*)(qw + i);
  f32x4 b = *(const f32x4*)(ow + i);
  f32x4 s = *(const f32x4*)(sg + i);
  uint2 pa, pb, ps;
  pa.x = (u32)f2bf(a[0]) | ((u32)f2bf(a[1]) << 16);
  pa.y = (u32)f2bf(a[2]) | ((u32)f2bf(a[3]) << 16);
  pb.x = (u32)f2bf(b[0]) | ((u32)f2bf(b[1]) << 16);
  pb.y = (u32)f2bf(b[2]) | ((u32)f2bf(b[3]) << 16);
  float t0 = (s[0] > 0.3f) ? 1.0f : ((s[0] < -0.3f) ? -1.0f : 0.0f);
  float t1 = (s[1] > 0.3f) ? 1.0f : ((s[1] < -0.3f) ? -1.0f : 0.0f);
  float t2 = (s[2] > 0.3f) ? 1.0f : ((s[2] < -0.3f) ? -1.0f : 0.0f);
  float t3 = (s[3] > 0.3f) ? 1.0f : ((s[3] < -0.3f) ? -1.0f : 0.0f);
  ps.x = (u32)f2bf(t0) | ((u32)f2bf(t1) << 16);
  ps.y = (u32)f2bf(t2) | ((u32)f2bf(t3) << 16);
  *(uint2*)(qwb + i) = pa;
  *(uint2*)(owb + i) = pb;
  *(uint2*)(sgb + i) = ps;
}

// ---------------- LayerNorm: one block per token ----------------
__global__ __launch_bounds__(256) void ln_kernel(
    const float* __restrict__ x, const float* __restrict__ g,
    const float* __restrict__ b, u16* __restrict__ xn){
  const int t = blockIdx.x, tid = threadIdx.x;
  f32x4 v = *(const f32x4*)(x + (size_t)t * 1024 + tid * 4);
  float s  = v[0] + v[1] + v[2] + v[3];
  float ss = v[0]*v[0] + v[1]*v[1] + v[2]*v[2] + v[3]*v[3];
  for (int off = 32; off; off >>= 1){
    s  += __shfl_down(s, off);
    ss += __shfl_down(ss, off);
  }
  __shared__ float red[8];
  int w = tid >> 6;
  if ((tid & 63) == 0){ red[w] = s; red[4 + w] = ss; }
  __syncthreads();
  s  = red[0] + red[1] + red[2] + red[3];
  ss = red[4] + red[5] + red[6] + red[7];
  float mean = s * (1.0f / 1024.0f);
  float var  = ss * (1.0f / 1024.0f) - mean * mean;   // jnp.var (ddof=0)
  float rs   = rsqrtf(var + 1e-5f);
  f32x4 gv = *(const f32x4*)(g + tid * 4);
  f32x4 bv = *(const f32x4*)(b + tid * 4);
  float y0 = (v[0]-mean)*rs*gv[0]+bv[0];
  float y1 = (v[1]-mean)*rs*gv[1]+bv[1];
  float y2 = (v[2]-mean)*rs*gv[2]+bv[2];
  float y3 = (v[3]-mean)*rs*gv[3]+bv[3];
  uint2 pk;
  pk.x = (u32)f2bf(y0) | ((u32)f2bf(y1) << 16);
  pk.y = (u32)f2bf(y2) | ((u32)f2bf(y3) << 16);
  *(uint2*)(xn + (size_t)t * 1024 + tid * 4) = pk;
}

// ---------------- bf16 MFMA GEMM: C[m,n] = sum_k A[m,k]*B[n,k] (+epilogue) ----------------
// M=8192, N=1024, K=1024. 128x128 tile, 4 waves in 2x2, each wave 64x64 (4x4 MFMA 16x16x32).
// DOUBLE-BUFFERED LDS (2x32KB): stage(kt+1) issued right after the barrier so the
// global->LDS DMA overlaps the 32-MFMA compute of kt; ONE barrier per kt-iter
// (R6 structure: stage->barrier->compute = full L2 latency exposed every iter).
// Grid = 512 1-D, XCD-swizzled: XCD (b%8) owns a contiguous 1024-row A-stripe.
// LDS unpadded 64-u16 stride, XOR-swizzled: chunk g (16B) of row s at pos g^(s&7).
// mode 0: outb[m,n] = bf16(C + bias[n]);  mode 1: outf[m,n] = C + bias[n] + resid[m,n]
__global__ __launch_bounds__(256, 2) void gemm_bt(
    const u16* __restrict__ A, const u16* __restrict__ B,
    const float* __restrict__ bias, const float* __restrict__ resid,
    float* __restrict__ outf, u16* __restrict__ outb, int mode){
  __shared__ u16 As[2][128 * 64];   // 2 x 16 KB
  __shared__ u16 Bs[2][128 * 64];
  const int tid = threadIdx.x;
  const int b = blockIdx.x;
  const int m0 = ((b & 7) * 8 + ((b >> 3) & 7)) * 128;   // XCD-contiguous m-stripe
  const int n0 = (b >> 6) * 128;
  const int w = tid >> 6, lane = tid & 63, lm = lane & 15, quad = lane >> 4;
  const int wm = (w & 1) * 64, wn = (w >> 1) * 64;
  const int lr = lane >> 3;                 // row-within-8 of this lane's staging chunk
  const int lg = (lane & 7) ^ lr;           // swizzled source chunk id
  const f32x4 fz = {0.f, 0.f, 0.f, 0.f};
  f32x4 acc[4][4];
  #pragma unroll
  for (int i = 0; i < 4; ++i)
    #pragma unroll
    for (int j = 0; j < 4; ++j) acc[i][j] = fz;

  const u16* gA = A + (size_t)(m0 + w * 32 + lr) * 1024 + lg * 8;
  const u16* gB = B + (size_t)(n0 + w * 32 + lr) * 1024 + lg * 8;
  const int lbase = (w * 32) * 64;          // wave-uniform LDS offset (u16)
  const int sw = lm & 7;

  auto stage = [&](int kt, int bb){
    #pragma unroll
    for (int sub = 0; sub < 4; ++sub){
      gld16(gA + (size_t)(sub * 8) * 1024 + kt * 64, &As[bb][lbase + sub * 8 * 64]);
      gld16(gB + (size_t)(sub * 8) * 1024 + kt * 64, &Bs[bb][lbase + sub * 8 * 64]);
    }
  };

  stage(0, 0);
  for (int kt = 0; kt < 16; ++kt){
    __syncthreads();                        // drains stage(kt); buffers now valid
    if (kt < 15) stage(kt + 1, (kt + 1) & 1);   // overlaps compute below
    const u16* as = As[kt & 1];
    const u16* bs = Bs[kt & 1];
    #pragma unroll
    for (int kk = 0; kk < 2; ++kk){
      const int ch = ((quad + kk * 4) ^ sw) * 8;   // swizzled chunk offset (u16)
      bf16x8 afr[4], bfr[4];
      #pragma unroll
      for (int i = 0; i < 4; ++i)
        afr[i] = *(const bf16x8*)(&as[(wm + i * 16 + lm) * 64 + ch]);
      #pragma unroll
      for (int j = 0; j < 4; ++j)
        bfr[j] = *(const bf16x8*)(&bs[(wn + j * 16 + lm) * 64 + ch]);
      #pragma unroll
      for (int i = 0; i < 4; ++i)
        #pragma unroll
        for (int j = 0; j < 4; ++j)
          acc[i][j] = __builtin_amdgcn_mfma_f32_16x16x32_bf16(afr[i], bfr[j], acc[i][j], 0, 0, 0);
    }
  }

  #pragma unroll
  for (int i = 0; i < 4; ++i){
    #pragma unroll
    for (int r = 0; r < 4; ++r){
      int grow = m0 + wm + i * 16 + quad * 4 + r;
      #pragma unroll
      for (int j = 0; j < 4; ++j){
        int gcol = n0 + wn + j * 16 + lm;
        float v = acc[i][j][r] + bias[gcol];
        if (mode){
          v += resid[(size_t)grow * 1024 + gcol];
          outf[(size_t)grow * 1024 + gcol] = v;
        } else {
          outb[(size_t)grow * 1024 + gcol] = f2bf(v);
        }
      }
    }
  }
}

// ---------------- fused scores + top2 + softmax + gather ----------------
// block = 128 tokens x 1 head; 4 waves, wave w owns tokens [w*32, w*32+32).
// TRANSPOSED 16x16x32 MFMA: sig group (16 slots) = A operand, q tokens = B.
// Each wave runs TWO token-sets (lm and lm+16) reusing the same sig frags.
// Lane state per set: acc f32x4 + (v1,v2 keyed floats, b1,b2 group ids) —
// total hot state ~60 regs, nothing for the allocator to park in AGPRs
// (R6: rk[16] table + f32x16 fzero + f32x16 acc => ~160 regs/wave total,
// AGPR parking, 2.3 blocks/CU, latency-bound).
// Key packing: low 4 mantissa bits = slot-in-group (quad*4+r), <=2^-19 rel.
__global__ __launch_bounds__(256) void route_kernel(
    const u16* __restrict__ q, const u16* __restrict__ sig,
    const float* __restrict__ V, const float* __restrict__ temp,
    u16* __restrict__ rd){
  const int h = blockIdx.y;
  const int t0 = blockIdx.x * 128;
  const int tid = threadIdx.x, w = tid >> 6, lane = tid & 63;
  const int lm = lane & 15, quad = lane >> 4;

  __shared__ u16 sbuf[2][128 * 64];         // 2 x 16 KB, swizzled
  __shared__ float fw1[128], fw2[128];
  __shared__ int   fi1[128], fi2[128];

  // q B-frags (loop-invariant): set s -> token t0 + w*32 + s*16 + lm; k = quad*8+j (+32)
  const u16* q0 = q + (size_t)(t0 + w * 32 + lm) * 1024 + h * 64 + quad * 8;
  bf16x8 qf00 = *(const bf16x8*)(q0);
  bf16x8 qf01 = *(const bf16x8*)(q0 + 32);
  bf16x8 qf10 = *(const bf16x8*)(q0 + 16 * 1024);
  bf16x8 qf11 = *(const bf16x8*)(q0 + 16 * 1024 + 32);

  const u16* sigh = sig + (size_t)h * 65536;

  // staging: wave w stages rows [w*32, w*32+32) of the 128-slot tile.
  // 8 lanes per row (16B chunks); swizzle: LDS pos p of row s holds chunk p^(s&7).
  const int lr = lane >> 3, lg = (lane & 7) ^ lr;
  const u16* ssrc = sigh + (size_t)(w * 32 + lr) * 64 + lg * 8;
  auto stage = [&](int t, int bb){
    const u16* s0 = ssrc + (size_t)t * 128 * 64;
    u16* d0 = &sbuf[bb][(w * 32) * 64];
    #pragma unroll
    for (int sub = 0; sub < 4; ++sub)
      gld16(s0 + sub * 8 * 64, d0 + sub * 8 * 64);
  };

  // sig frag LDS offsets (u16 units), loop-invariant: row lm of group g,
  // chunk quad (k 0..31) at pos quad^(lm&7); chunk quad+4 at pos^4.
  const int base1 = lm * 64 + ((quad ^ (lm & 7)) * 8);
  const int base2 = base1 ^ 32;             // pos^4 -> +-32 u16

  const f32x4 fz4 = {0.f, 0.f, 0.f, 0.f};
  const u32 vq = (u32)(quad * 4);
  float v1a = -3.0e38f, v2a = -3.0e38f, v1b = -3.0e38f, v2b = -3.0e38f;
  u32 b1a = 0, b2a = 0, b1b = 0, b2b = 0;

  stage(0, 0);
  for (int t = 0; t < 8; ++t){
    __syncthreads();                         // drains vmcnt: staging of buf t&1 visible
    if (t < 7) stage(t + 1, (t + 1) & 1);
    const u16* buf = sbuf[t & 1];
    #pragma unroll
    for (int g = 0; g < 8; ++g){
      bf16x8 s1 = *(const bf16x8*)(&buf[g * 1024 + base1]);
      bf16x8 s2 = *(const bf16x8*)(&buf[g * 1024 + base2]);
      u32 bt = (u32)(t * 8 + g);
      #pragma unroll
      for (int set = 0; set < 2; ++set){
        f32x4 acc = __builtin_amdgcn_mfma_f32_16x16x32_bf16(s1, set ? qf10 : qf00, fz4, 0, 0, 0);
        acc       = __builtin_amdgcn_mfma_f32_16x16x32_bf16(s2, set ? qf11 : qf01, acc, 0, 0, 0);
        float k0 = __uint_as_float((__float_as_uint(acc[0]) & 0xFFFFFFF0u) | vq);
        float k1 = __uint_as_float((__float_as_uint(acc[1]) & 0xFFFFFFF0u) | (vq + 1u));
        float k2 = __uint_as_float((__float_as_uint(acc[2]) & 0xFFFFFFF0u) | (vq + 2u));
        float k3 = __uint_as_float((__float_as_uint(acc[3]) & 0xFFFFFFF0u) | (vq + 3u));
        float h1 = fmaxf(k0, k1), h2 = fminf(k0, k1);
        float h3 = fmaxf(k2, k3), h4 = fminf(k2, k3);
        float m1 = fmaxf(h1, h3);
        float m2 = __builtin_amdgcn_fmed3f(h1, h3, fmaxf(h2, h4));
        float v1 = set ? v1b : v1a, v2 = set ? v2b : v2a;
        u32   b1 = set ? b1b : b1a, b2 = set ? b2b : b2a;
        u32   cb2 = (m2 > v2) ? bt : b2;
        float c2  = fmaxf(v2, m2);
        u32   nb1 = (m1 > v1) ? bt : b1;
        float n1  = fmaxf(v1, m1);
        float n2  = __builtin_amdgcn_fmed3f(v1, m1, c2);
        u32   nb2 = (n2 == m1) ? bt : ((n2 == v1) ? b1 : cb2);
        if (set){ v1b = n1; b1b = nb1; v2b = n2; b2b = nb2; }
        else    { v1a = n1; b1a = nb1; v2a = n2; b2a = nb2; }
      }
    }
  }

  // cross-quad butterfly (offsets 16, 32): quads hold disjoint slot-in-group
  // ids (key low bits quad*4+r), so keys never collide on one slot.
  #pragma unroll
  for (int off = 16; off <= 32; off <<= 1){
    #pragma unroll
    for (int set = 0; set < 2; ++set){
      float v1 = set ? v1b : v1a, v2 = set ? v2b : v2a;
      u32   b1 = set ? b1b : b1a, b2 = set ? b2b : b2a;
      float o1 = __shfl_xor(v1, off);
      float o2 = __shfl_xor(v2, off);
      u32 ob1 = (u32)__shfl_xor((int)b1, off);
      u32 ob2 = (u32)__shfl_xor((int)b2, off);
      u32   cb2 = (o2 > v2) ? ob2 : b2;
      float c2  = fmaxf(v2, o2);
      u32   nb1 = (o1 > v1) ? ob1 : b1;
      float n1  = fmaxf(v1, o1);
      float n2  = __builtin_amdgcn_fmed3f(v1, o1, c2);
      u32   nb2 = (n2 == o1) ? ob1 : ((n2 == v1) ? b1 : cb2);
      if (set){ v1b = n1; b1b = nb1; v2b = n2; b2b = nb2; }
      else    { v1a = n1; b1a = nb1; v2a = n2; b2a = nb2; }
    }
  }

  if (quad == 0){                            // lanes 0..15 of each wave
    float tsc = 1.0f / (temp[0] * 8.0f);     // 1/(temperature*sqrt(64))
    #pragma unroll
    for (int set = 0; set < 2; ++set){
      float v1 = set ? v1b : v1a, v2 = set ? v2b : v2a;
      u32   b1 = set ? b1b : b1a, b2 = set ? b2b : b2a;
      int tl = w * 32 + set * 16 + lm;
      u32 u1 = __float_as_uint(v1);
      u32 u2 = __float_as_uint(v2);
      float s1 = __uint_as_float(u1 & 0xFFFFFFF0u);
      float s2 = __uint_as_float(u2 & 0xFFFFFFF0u);
      float ex = __expf((s2 - s1) * tsc);    // <= 1, stable
      float iw = 1.0f / (1.0f + ex);
      fw1[tl] = iw; fw2[tl] = ex * iw;
      fi1[tl] = (int)(b1 * 16 + (u1 & 15u));
      fi2[tl] = (int)(b2 * 16 + (u2 & 15u));
    }
  }
  __syncthreads();

  // gather: token = tid>>1, dims [(tid&1)*32, +32)
  int tl = tid >> 1, d0 = (tid & 1) * 32;
  const float* va = V + ((size_t)h * 1024 + fi1[tl]) * 64 + d0;
  const float* vb = V + ((size_t)h * 1024 + fi2[tl]) * 64 + d0;
  float W1 = fw1[tl], W2 = fw2[tl];
  u16* dst = rd + (size_t)(t0 + tl) * 1024 + h * 64 + d0;
  #pragma unroll
  for (int g = 0; g < 4; ++g){
    f32x4 xa = *(const f32x4*)(va + g * 8);
    f32x4 xb = *(const f32x4*)(va + g * 8 + 4);
    f32x4 ya = *(const f32x4*)(vb + g * 8);
    f32x4 yb = *(const f32x4*)(vb + g * 8 + 4);
    uint4 o;
    o.x = (u32)f2bf(W1*xa[0]+W2*ya[0]) | ((u32)f2bf(W1*xa[1]+W2*ya[1]) << 16);
    o.y = (u32)f2bf(W1*xa[2]+W2*ya[2]) | ((u32)f2bf(W1*xa[3]+W2*ya[3]) << 16);
    o.z = (u32)f2bf(W1*xb[0]+W2*yb[0]) | ((u32)f2bf(W1*xb[1]+W2*yb[1]) << 16);
    o.w = (u32)f2bf(W1*xb[2]+W2*yb[2]) | ((u32)f2bf(W1*xb[3]+W2*yb[3]) << 16);
    *(uint4*)(dst + g * 8) = o;
  }
}

extern "C" void kernel_launch(void* const* d_in, const int* in_sizes, int n_in,
                              void* d_out, int out_size, void* d_ws, size_t ws_size,
                              hipStream_t stream){
  const float* x    = (const float*)d_in[0];
  const float* lng  = (const float*)d_in[1];
  const float* lnb  = (const float*)d_in[2];
  const float* qw   = (const float*)d_in[3];
  const float* qb   = (const float*)d_in[4];
  const float* sig  = (const float*)d_in[5];
  const float* sv   = (const float*)d_in[6];
  const float* ow   = (const float*)d_in[7];
  const float* ob   = (const float*)d_in[8];
  const float* temp = (const float*)d_in[9];
  float* out = (float*)d_out;

  char* ws = (char*)d_ws;
  u16* xn   = (u16*)(ws);                                  // 16 MiB  (x_norm bf16; reused as `read`)
  u16* qwb  = (u16*)(ws + 16777216);                       //  2 MiB
  u16* owb  = (u16*)(ws + 16777216 + 2097152);             //  2 MiB
  u16* sgb  = (u16*)(ws + 16777216 + 2 * 2097152);         //  2 MiB
  u16* qb16 = (u16*)(ws + 16777216 + 3 * 2097152);         // 16 MiB  (q bf16)
  u16* rdb  = xn;                                          // alias: x_norm dead after GEMM1

  convert_kernel<<<1024, 256, 0, stream>>>(qw, ow, sig, qwb, owb, sgb);
  ln_kernel<<<8192, 256, 0, stream>>>(x, lng, lnb, xn);
  gemm_bt<<<512, 256, 0, stream>>>(xn, qwb, qb, nullptr, nullptr, qb16, 0);
  route_kernel<<<dim3(64, 16), 256, 0, stream>>>(qb16, sgb, sv, temp, rdb);
  gemm_bt<<<512, 256, 0, stream>>>(rdb, owb, ob, x, out, nullptr, 1);
}

// Round 8
// 210.668 us; speedup vs baseline: 1.0306x; 1.0306x over previous
//
#include <hip/hip_runtime.h>

typedef unsigned short u16;
typedef unsigned int   u32;
typedef float f32x4  __attribute__((ext_vector_type(4)));
typedef float f32x16 __attribute__((ext_vector_type(16)));
typedef __bf16 bf16x8 __attribute__((ext_vector_type(8)));

__device__ __forceinline__ u16 f2bf(float f){
  u32 u = __float_as_uint(f);
  u += 0x7fffu + ((u >> 16) & 1u);          // RNE
  return (u16)(u >> 16);
}

// async global->LDS, 16B per lane; LDS dest is wave-uniform base + lane*16
__device__ __forceinline__ void gld16(const void* g, void* l){
  __builtin_amdgcn_global_load_lds((const __attribute__((address_space(1))) u32*)g,
                                   (__attribute__((address_space(3))) u32*)l, 16, 0, 0);
}

// s_waitcnt immediates (gfx9 encoding: vmcnt[3:0]|exp[6:4]|lgkm[11:8]|vmcnt_hi[15:14])
#define WAITCNT_VM0   0x0F70   // vmcnt(0),  lgkm/exp ignored
#define WAITCNT_VM4   0x0F74   // vmcnt(4)
#define WAITCNT_LGKM0 0xC07F   // lgkmcnt(0), vmcnt/exp ignored

// ---------------- weight conversion: fp32->bf16, sigs->ternary bf16 ----------------
__global__ __launch_bounds__(256) void convert_kernel(
    const float* __restrict__ qw, const float* __restrict__ ow,
    const float* __restrict__ sg,
    u16* __restrict__ qwb, u16* __restrict__ owb, u16* __restrict__ sgb){
  int i = (blockIdx.x * 256 + threadIdx.x) * 4;   // 1,048,576 elements each
  f32x4 a = *(const f32x4*)(qw + i);
  f32x4 b = *(const f32x4*)(ow + i);
  f32x4 s = *(const f32x4*)(sg + i);
  uint2 pa, pb, ps;
  pa.x = (u32)f2bf(a[0]) | ((u32)f2bf(a[1]) << 16);
  pa.y = (u32)f2bf(a[2]) | ((u32)f2bf(a[3]) << 16);
  pb.x = (u32)f2bf(b[0]) | ((u32)f2bf(b[1]) << 16);
  pb.y = (u32)f2bf(b[2]) | ((u32)f2bf(b[3]) << 16);
  float t0 = (s[0] > 0.3f) ? 1.0f : ((s[0] < -0.3f) ? -1.0f : 0.0f);
  float t1 = (s[1] > 0.3f) ? 1.0f : ((s[1] < -0.3f) ? -1.0f : 0.0f);
  float t2 = (s[2] > 0.3f) ? 1.0f : ((s[2] < -0.3f) ? -1.0f : 0.0f);
  float t3 = (s[3] > 0.3f) ? 1.0f : ((s[3] < -0.3f) ? -1.0f : 0.0f);
  ps.x = (u32)f2bf(t0) | ((u32)f2bf(t1) << 16);
  ps.y = (u32)f2bf(t2) | ((u32)f2bf(t3) << 16);
  *(uint2*)(qwb + i) = pa;
  *(uint2*)(owb + i) = pb;
  *(uint2*)(sgb + i) = ps;
}

// ---------------- LayerNorm: one WAVE per token (no LDS, no barriers) ----------------
__global__ __launch_bounds__(256) void ln_kernel(
    const float* __restrict__ x, const float* __restrict__ g,
    const float* __restrict__ b, u16* __restrict__ xn){
  const int tid = threadIdx.x, lane = tid & 63, w = tid >> 6;
  const int t = blockIdx.x * 4 + w;
  const float* xr = x + (size_t)t * 1024;
  f32x4 v[4];
  #pragma unroll
  for (int j = 0; j < 4; ++j) v[j] = *(const f32x4*)(xr + j * 256 + lane * 4);
  float s = 0.f, ss = 0.f;
  #pragma unroll
  for (int j = 0; j < 4; ++j)
    #pragma unroll
    for (int e = 0; e < 4; ++e){ s += v[j][e]; ss += v[j][e] * v[j][e]; }
  #pragma unroll
  for (int off = 32; off; off >>= 1){
    s  += __shfl_xor(s, off);
    ss += __shfl_xor(ss, off);
  }
  float mean = s * (1.0f / 1024.0f);
  float var  = ss * (1.0f / 1024.0f) - mean * mean;   // jnp.var (ddof=0)
  float rs   = rsqrtf(var + 1e-5f);
  #pragma unroll
  for (int j = 0; j < 4; ++j){
    f32x4 gv = *(const f32x4*)(g + j * 256 + lane * 4);
    f32x4 bv = *(const f32x4*)(b + j * 256 + lane * 4);
    float y0 = (v[j][0]-mean)*rs*gv[0]+bv[0];
    float y1 = (v[j][1]-mean)*rs*gv[1]+bv[1];
    float y2 = (v[j][2]-mean)*rs*gv[2]+bv[2];
    float y3 = (v[j][3]-mean)*rs*gv[3]+bv[3];
    uint2 pk;
    pk.x = (u32)f2bf(y0) | ((u32)f2bf(y1) << 16);
    pk.y = (u32)f2bf(y2) | ((u32)f2bf(y3) << 16);
    *(uint2*)(xn + (size_t)t * 1024 + j * 256 + lane * 4) = pk;
  }
}

// ---------------- bf16 MFMA GEMM: C[m,n] = sum_k A[m,k]*B[n,k] (+epilogue) ----------------
// M=8192, N=1024, K=1024. 128x128 tile, 4 waves in 2x2, each wave 64x64 (4x4 MFMA 16x16x32).
// DOUBLE-BUFFERED LDS, stage(kt+1) after the barrier overlaps compute of kt.
// Grid = 512 1-D, XCD-swizzled. LDS XOR-swizzled (chunk g of row s at pos g^(s&7)).
// mode 0: outb[m,n] = bf16(C + bias[n]);  mode 1: outf[m,n] = C + bias[n] + resid[m,n]
__global__ __launch_bounds__(256, 2) void gemm_bt(
    const u16* __restrict__ A, const u16* __restrict__ B,
    const float* __restrict__ bias, const float* __restrict__ resid,
    float* __restrict__ outf, u16* __restrict__ outb, int mode){
  __shared__ u16 As[2][128 * 64];   // 2 x 16 KB
  __shared__ u16 Bs[2][128 * 64];
  const int tid = threadIdx.x;
  const int b = blockIdx.x;
  const int m0 = ((b & 7) * 8 + ((b >> 3) & 7)) * 128;   // XCD-contiguous m-stripe
  const int n0 = (b >> 6) * 128;
  const int w = tid >> 6, lane = tid & 63, lm = lane & 15, quad = lane >> 4;
  const int wm = (w & 1) * 64, wn = (w >> 1) * 64;
  const int lr = lane >> 3;                 // row-within-8 of this lane's staging chunk
  const int lg = (lane & 7) ^ lr;           // swizzled source chunk id
  const f32x4 fz = {0.f, 0.f, 0.f, 0.f};
  f32x4 acc[4][4];
  #pragma unroll
  for (int i = 0; i < 4; ++i)
    #pragma unroll
    for (int j = 0; j < 4; ++j) acc[i][j] = fz;

  const u16* gA = A + (size_t)(m0 + w * 32 + lr) * 1024 + lg * 8;
  const u16* gB = B + (size_t)(n0 + w * 32 + lr) * 1024 + lg * 8;
  const int lbase = (w * 32) * 64;          // wave-uniform LDS offset (u16)
  const int sw = lm & 7;

  auto stage = [&](int kt, int bb){
    #pragma unroll
    for (int sub = 0; sub < 4; ++sub){
      gld16(gA + (size_t)(sub * 8) * 1024 + kt * 64, &As[bb][lbase + sub * 8 * 64]);
      gld16(gB + (size_t)(sub * 8) * 1024 + kt * 64, &Bs[bb][lbase + sub * 8 * 64]);
    }
  };

  stage(0, 0);
  for (int kt = 0; kt < 16; ++kt){
    __syncthreads();                        // drains stage(kt); buffers now valid
    if (kt < 15) stage(kt + 1, (kt + 1) & 1);   // overlaps compute below
    const u16* as = As[kt & 1];
    const u16* bs = Bs[kt & 1];
    #pragma unroll
    for (int kk = 0; kk < 2; ++kk){
      const int ch = ((quad + kk * 4) ^ sw) * 8;   // swizzled chunk offset (u16)
      bf16x8 afr[4], bfr[4];
      #pragma unroll
      for (int i = 0; i < 4; ++i)
        afr[i] = *(const bf16x8*)(&as[(wm + i * 16 + lm) * 64 + ch]);
      #pragma unroll
      for (int j = 0; j < 4; ++j)
        bfr[j] = *(const bf16x8*)(&bs[(wn + j * 16 + lm) * 64 + ch]);
      #pragma unroll
      for (int i = 0; i < 4; ++i)
        #pragma unroll
        for (int j = 0; j < 4; ++j)
          acc[i][j] = __builtin_amdgcn_mfma_f32_16x16x32_bf16(afr[i], bfr[j], acc[i][j], 0, 0, 0);
    }
  }

  #pragma unroll
  for (int i = 0; i < 4; ++i){
    #pragma unroll
    for (int r = 0; r < 4; ++r){
      int grow = m0 + wm + i * 16 + quad * 4 + r;
      #pragma unroll
      for (int j = 0; j < 4; ++j){
        int gcol = n0 + wn + j * 16 + lm;
        float v = acc[i][j][r] + bias[gcol];
        if (mode){
          v += resid[(size_t)grow * 1024 + gcol];
          outf[(size_t)grow * 1024 + gcol] = v;
        } else {
          outb[(size_t)grow * 1024 + gcol] = f2bf(v);
        }
      }
    }
  }
}

// top-2 merge of (value,id) pairs; keyed floats, ids ride along
#define MERGE2(V1,I1,V2,I2, o1,oi1,o2,oi2) {                      \
    u32   cb2 = (o2 > V2) ? oi2 : I2;                             \
    float c2  = fmaxf(V2, o2);                                    \
    u32   nb1 = (o1 > V1) ? oi1 : I1;                             \
    float n1  = fmaxf(V1, o1);                                    \
    float n2  = __builtin_amdgcn_fmed3f(V1, o1, c2);              \
    u32   nb2 = (n2 == o1) ? oi1 : ((n2 == V1) ? I1 : cb2);       \
    V1 = n1; I1 = nb1; V2 = n2; I2 = nb2; }

// ---------------- fused scores + top2 + softmax + gather ----------------
// block = 64 tokens x 1 head (grid 2048 = 8 blocks/CU backlog, 4 resident).
// NO BARRIERS in the hot loop: sig tiles are WAVE-PRIVATE (2 x 4KB dbuf per
// wave); each wave orders its own DMA with explicit s_waitcnt vmcnt(4)
// (never 0 in steady state — AITER-style), staging tile i+2 into the buffer
// of tile i only after lgkmcnt(0) retires tile i's ds_reads.
// Wave w scans slots [w*256,(w+1)*256) for all 64 tokens: TRANSPOSED
// 32x32x16 MFMA (sig rows = A, q tokens = B), 2 token-sets reuse the same
// sig frags. Per-set state = 2 keyed floats + 2 tile ids (4 regs).
// Key packing: low 5 mantissa bits = slot-row (<=2^-18 rel perturbation).
__global__ __launch_bounds__(256) void route_kernel(
    const u16* __restrict__ q, const u16* __restrict__ sig,
    const float* __restrict__ V, const float* __restrict__ temp,
    u16* __restrict__ rd){
  const int h = blockIdx.y;
  const int t0 = blockIdx.x * 64;
  const int tid = threadIdx.x, w = tid >> 6, lane = tid & 63;
  const int col = lane & 31, half = lane >> 5;

  __shared__ u16 sbuf[4][2][32 * 64];       // per-wave double buffers (32 KB)
  __shared__ float sv1[4][64], sv2[4][64];
  __shared__ u32   si1[4][64], si2[4][64];
  __shared__ float fw1[64], fw2[64];
  __shared__ int   fi1[64], fi2[64];

  // q B-frags (loop-invariant): set s -> token t0 + s*32 + col; k = c*16 + half*8 + j
  const u16* q0 = q + (size_t)(t0 + col) * 1024 + h * 64 + half * 8;
  bf16x8 qa[4], qb[4];
  #pragma unroll
  for (int c = 0; c < 4; ++c){
    qa[c] = *(const bf16x8*)(q0 + c * 16);
    qb[c] = *(const bf16x8*)(q0 + 32 * 1024 + c * 16);
  }
  __builtin_amdgcn_s_waitcnt(WAITCNT_VM0);  // q in regs; loop vmcnt counts only DMAs

  // staging: wave w's tile i = slots w*256 + i*32 .. +32. 8 lanes/row (16B chunks),
  // swizzle: LDS pos p of row s holds source chunk p^(s&7).
  const int lr = lane >> 3, lg = (lane & 7) ^ lr;
  const u16* ssrc = sig + (size_t)h * 65536 + (size_t)(w * 256 + lr) * 64 + lg * 8;
  auto stage = [&](int i, int bb){
    const u16* s0 = ssrc + (size_t)i * 32 * 64;
    u16* d0 = &sbuf[w][bb][0];
    #pragma unroll
    for (int sub = 0; sub < 4; ++sub)
      gld16(s0 + sub * 8 * 64, d0 + sub * 8 * 64);
  };

  // sig A-frag LDS offsets (u16), loop-invariant: row col, chunk (2c+half)^(col&7)
  int p[4];
  #pragma unroll
  for (int c = 0; c < 4; ++c) p[c] = col * 64 + (((2 * c + half) ^ (col & 7)) * 8);

  const f32x16 fzero = {};
  float v1a = -3.0e38f, v2a = -3.0e38f, v1b = -3.0e38f, v2b = -3.0e38f;
  u32 b1a = 0, b2a = 0, b1b = 0, b2b = 0;

  stage(0, 0);
  stage(1, 1);                               // 8 DMAs outstanding
  #pragma unroll
  for (int i = 0; i < 8; ++i){
    if (i < 7) __builtin_amdgcn_s_waitcnt(WAITCNT_VM4);  // tile i landed, i+1 in flight
    else       __builtin_amdgcn_s_waitcnt(WAITCNT_VM0);
    const u16* buf = sbuf[w][i & 1];
    bf16x8 sf0 = *(const bf16x8*)(&buf[p[0]]);
    bf16x8 sf1 = *(const bf16x8*)(&buf[p[1]]);
    bf16x8 sf2 = *(const bf16x8*)(&buf[p[2]]);
    bf16x8 sf3 = *(const bf16x8*)(&buf[p[3]]);
    __builtin_amdgcn_s_waitcnt(WAITCNT_LGKM0);           // frags in regs
    if (i < 6) stage(i + 2, i & 1);                      // safe buffer reuse
    u32 bt = (u32)i;
    #pragma unroll
    for (int set = 0; set < 2; ++set){
      f32x16 acc;
      acc = __builtin_amdgcn_mfma_f32_32x32x16_bf16(sf0, set ? qb[0] : qa[0], fzero, 0, 0, 0);
      acc = __builtin_amdgcn_mfma_f32_32x32x16_bf16(sf1, set ? qb[1] : qa[1], acc, 0, 0, 0);
      acc = __builtin_amdgcn_mfma_f32_32x32x16_bf16(sf2, set ? qb[2] : qa[2], acc, 0, 0, 0);
      acc = __builtin_amdgcn_mfma_f32_32x32x16_bf16(sf3, set ? qb[3] : qa[3], acc, 0, 0, 0);
      // pack 16 keys: masked score | slot-row ((r&3)+8*(r>>2)+4*half)
      float k[16];
      #pragma unroll
      for (int r = 0; r < 16; ++r){
        u32 rk = (u32)((r & 3) + 8 * (r >> 2) + 4 * half);
        k[r] = __uint_as_float((__float_as_uint(acc[r]) & 0xFFFFFFE0u) | rk);
      }
      float h1[8], h2[8];
      #pragma unroll
      for (int j = 0; j < 8; ++j){
        h1[j] = fmaxf(k[2*j], k[2*j+1]);
        h2[j] = fminf(k[2*j], k[2*j+1]);
      }
      float g1[4], g2[4];
      #pragma unroll
      for (int j = 0; j < 4; ++j){
        g1[j] = fmaxf(h1[2*j], h1[2*j+1]);
        g2[j] = __builtin_amdgcn_fmed3f(h1[2*j], h1[2*j+1], fmaxf(h2[2*j], h2[2*j+1]));
      }
      float e1[2], e2[2];
      #pragma unroll
      for (int j = 0; j < 2; ++j){
        e1[j] = fmaxf(g1[2*j], g1[2*j+1]);
        e2[j] = __builtin_amdgcn_fmed3f(g1[2*j], g1[2*j+1], fmaxf(g2[2*j], g2[2*j+1]));
      }
      float m1 = fmaxf(e1[0], e1[1]);
      float m2 = __builtin_amdgcn_fmed3f(e1[0], e1[1], fmaxf(e2[0], e2[1]));
      if (set){ MERGE2(v1b, b1b, v2b, b2b, m1, bt, m2, bt); }
      else    { MERGE2(v1a, b1a, v2a, b2a, m1, bt, m2, bt); }
    }
  }

  // cross-half merge (rowkeys include 4*half -> no collisions)
  #pragma unroll
  for (int set = 0; set < 2; ++set){
    float v1 = set ? v1b : v1a, v2 = set ? v2b : v2a;
    u32   b1 = set ? b1b : b1a, b2 = set ? b2b : b2a;
    float o1 = __shfl_xor(v1, 32);
    float o2 = __shfl_xor(v2, 32);
    u32 ob1 = (u32)__shfl_xor((int)b1, 32);
    u32 ob2 = (u32)__shfl_xor((int)b2, 32);
    MERGE2(v1, b1, v2, b2, o1, ob1, o2, ob2);
    if (half == 0){
      int tk = set * 32 + col;
      sv1[w][tk] = v1; sv2[w][tk] = v2;
      si1[w][tk] = (u32)(w * 256) + b1 * 32 + (__float_as_uint(v1) & 31u);  // full slot
      si2[w][tk] = (u32)(w * 256) + b2 * 32 + (__float_as_uint(v2) & 31u);
    }
  }
  __syncthreads();

  if (tid < 64){                             // token tid: merge the 4 waves
    float V1 = sv1[0][tid], V2 = sv2[0][tid];
    u32   I1 = si1[0][tid], I2 = si2[0][tid];
    #pragma unroll
    for (int ws = 1; ws < 4; ++ws){
      float o1 = sv1[ws][tid], o2 = sv2[ws][tid];
      u32  oi1 = si1[ws][tid], oi2 = si2[ws][tid];
      MERGE2(V1, I1, V2, I2, o1, oi1, o2, oi2);
    }
    float s1 = __uint_as_float(__float_as_uint(V1) & 0xFFFFFFE0u);
    float s2 = __uint_as_float(__float_as_uint(V2) & 0xFFFFFFE0u);
    float tsc = 1.0f / (temp[0] * 8.0f);     // 1/(temperature*sqrt(64))
    float ex = __expf((s2 - s1) * tsc);      // <= 1, stable
    float iw = 1.0f / (1.0f + ex);
    fw1[tid] = iw; fw2[tid] = ex * iw;
    fi1[tid] = (int)I1; fi2[tid] = (int)I2;
  }
  __syncthreads();

  // gather: token = tid>>2, dims [(tid&3)*16, +16)
  int tl = tid >> 2, d0 = (tid & 3) * 16;
  const float* va = V + ((size_t)h * 1024 + fi1[tl]) * 64 + d0;
  const float* vb = V + ((size_t)h * 1024 + fi2[tl]) * 64 + d0;
  float W1 = fw1[tl], W2 = fw2[tl];
  u16* dst = rd + (size_t)(t0 + tl) * 1024 + h * 64 + d0;
  #pragma unroll
  for (int g = 0; g < 2; ++g){
    f32x4 xa = *(const f32x4*)(va + g * 8);
    f32x4 xb = *(const f32x4*)(va + g * 8 + 4);
    f32x4 ya = *(const f32x4*)(vb + g * 8);
    f32x4 yb = *(const f32x4*)(vb + g * 8 + 4);
    uint4 o;
    o.x = (u32)f2bf(W1*xa[0]+W2*ya[0]) | ((u32)f2bf(W1*xa[1]+W2*ya[1]) << 16);
    o.y = (u32)f2bf(W1*xa[2]+W2*ya[2]) | ((u32)f2bf(W1*xa[3]+W2*ya[3]) << 16);
    o.z = (u32)f2bf(W1*xb[0]+W2*yb[0]) | ((u32)f2bf(W1*xb[1]+W2*yb[1]) << 16);
    o.w = (u32)f2bf(W1*xb[2]+W2*yb[2]) | ((u32)f2bf(W1*xb[3]+W2*yb[3]) << 16);
    *(uint4*)(dst + g * 8) = o;
  }
}

extern "C" void kernel_launch(void* const* d_in, const int* in_sizes, int n_in,
                              void* d_out, int out_size, void* d_ws, size_t ws_size,
                              hipStream_t stream){
  const float* x    = (const float*)d_in[0];
  const float* lng  = (const float*)d_in[1];
  const float* lnb  = (const float*)d_in[2];
  const float* qw   = (const float*)d_in[3];
  const float* qb   = (const float*)d_in[4];
  const float* sig  = (const float*)d_in[5];
  const float* sv   = (const float*)d_in[6];
  const float* ow   = (const float*)d_in[7];
  const float* ob   = (const float*)d_in[8];
  const float* temp = (const float*)d_in[9];
  float* out = (float*)d_out;

  char* ws = (char*)d_ws;
  u16* xn   = (u16*)(ws);                                  // 16 MiB  (x_norm bf16; reused as `read`)
  u16* qwb  = (u16*)(ws + 16777216);                       //  2 MiB
  u16* owb  = (u16*)(ws + 16777216 + 2097152);             //  2 MiB
  u16* sgb  = (u16*)(ws + 16777216 + 2 * 2097152);         //  2 MiB
  u16* qb16 = (u16*)(ws + 16777216 + 3 * 2097152);         // 16 MiB  (q bf16)
  u16* rdb  = xn;                                          // alias: x_norm dead after GEMM1

  convert_kernel<<<1024, 256, 0, stream>>>(qw, ow, sig, qwb, owb, sgb);
  ln_kernel<<<2048, 256, 0, stream>>>(x, lng, lnb, xn);
  gemm_bt<<<512, 256, 0, stream>>>(xn, qwb, qb, nullptr, nullptr, qb16, 0);
  route_kernel<<<dim3(128, 16), 256, 0, stream>>>(qb16, sgb, sv, temp, rdb);
  gemm_bt<<<512, 256, 0, stream>>>(rdb, owb, ob, x, out, nullptr, 1);
}